// Round 5
// baseline (514.226 us; speedup 1.0000x reference)
//
#include <hip/hip_runtime.h>
#include <cstdint>

#define F_IN 128
#define F_HID 16
#define PB 1024           // partition block threads
#define PT 4096           // edges per partition tile
#define NBMAX 512         // max buckets (nodes/256), n <= 131072

// ===========================================================================
// PATH NEW: counting-sort partition into 256-node dst buckets, then
// LDS-atomic aggregation per bucket. Packed edge word: r | (c&255)<<17.
// ===========================================================================

__global__ __launch_bounds__(PB) void partition_kernel(
    const int* __restrict__ row, const int* __restrict__ col,
    int* __restrict__ cursor,        // [NBMAX], zeroed
    int* __restrict__ packed_out,    // [NB * capB]
    int capB, int NB, int n_edges) {
    __shared__ int sh_hist[NBMAX];
    __shared__ int sh_scan[NBMAX];   // inclusive scan of hist
    __shared__ int sh_cur[NBMAX];    // scatter cursors (start = exclusive)
    __shared__ int sh_base[NBMAX];   // global base for this tile's runs
    __shared__ int sh_packed[PT];
    __shared__ unsigned short sh_bkt[PT];

    int t = threadIdx.x;
    int ntiles = (n_edges + PT - 1) / PT;

    for (int tile = blockIdx.x; tile < ntiles; tile += gridDim.x) {
        int tbase = tile * PT;
        int tcnt = min(PT, n_edges - tbase);

        if (t < NBMAX) sh_hist[t] = 0;
        __syncthreads();

        // load up to 4 edges/thread, histogram
        int pk[4], bb[4];
#pragma unroll
        for (int k = 0; k < 4; k++) {
            int e = tbase + t + k * PB;
            bb[k] = -1;
            if (e < n_edges) {
                int r = row[e];
                int c = col[e];
                bb[k] = c >> 8;
                pk[k] = r | ((c & 255) << 17);
                atomicAdd(&sh_hist[bb[k]], 1);
            }
        }
        __syncthreads();

        // inclusive scan of sh_hist -> sh_scan (512 wide)
        if (t < NBMAX) sh_scan[t] = sh_hist[t];
        __syncthreads();
        for (int off = 1; off < NBMAX; off <<= 1) {
            int v = 0;
            if (t < NBMAX && t >= off) v = sh_scan[t - off];
            __syncthreads();
            if (t < NBMAX) sh_scan[t] += v;
            __syncthreads();
        }
        // reserve global runs; init scatter cursors to exclusive offsets
        if (t < NBMAX) {
            int h = sh_hist[t];
            sh_cur[t] = sh_scan[t] - h;
            sh_base[t] = (h > 0 && t < NB) ? atomicAdd(&cursor[t], h) : 0;
        }
        __syncthreads();

        // LDS reorder scatter
#pragma unroll
        for (int k = 0; k < 4; k++) {
            if (bb[k] >= 0) {
                int p = atomicAdd(&sh_cur[bb[k]], 1);
                sh_packed[p] = pk[k];
                sh_bkt[p] = (unsigned short)bb[k];
            }
        }
        __syncthreads();

        // write runs out bucket-contiguously
#pragma unroll
        for (int k = 0; k < 4; k++) {
            int p = t + k * PB;
            if (p < tcnt) {
                int b = sh_bkt[p];
                int off = p - (sh_scan[b] - sh_hist[b]);  // rank within run
                int gp = sh_base[b] + off;
                if (gp < capB) packed_out[(size_t)b * capB + gp] = sh_packed[p];
            }
        }
        __syncthreads();
    }
}

// per-node degrees from packed buckets
__global__ __launch_bounds__(PB) void bucket_count_kernel(
    const int* __restrict__ cursor, const int* __restrict__ packed,
    int* __restrict__ cnt, int capB, int n) {
    __shared__ int scnt[256];
    int b = blockIdx.x, t = threadIdx.x;
    if (t < 256) scnt[t] = 0;
    __syncthreads();
    int cb = min(cursor[b], capB);
    const int* pp = packed + (size_t)b * capB;
    for (int i = t; i < cb; i += PB) {
        atomicAdd(&scnt[(pp[i] >> 17) & 255], 1);
    }
    __syncthreads();
    if (t < 256) {
        int g = b * 256 + t;
        if (g < n) cnt[g] = scnt[t];
    }
}

// layer-1 aggregation: LDS float atomics into acc[256][16], fused epilogue
__global__ __launch_bounds__(PB) void agg1_kernel(
    const int* __restrict__ cursor, const int* __restrict__ packed,
    const float* __restrict__ h1p, const int* __restrict__ cnt,
    const float* __restrict__ b1, const float* __restrict__ W2,
    float* __restrict__ sp, int capB, int n) {
    __shared__ float acc[256 * F_HID];  // 16 KB
    int b = blockIdx.x, t = threadIdx.x;
#pragma unroll
    for (int k = 0; k < 4; k++) acc[t + k * PB] = 0.0f;
    __syncthreads();

    int cb = min(cursor[b], capB);
    const int* pp = packed + (size_t)b * capB;
    int sub = t >> 4;        // edge slot within pass (0..63)
    int lane = t & 15;       // feature
    for (int base = 0; base < cb; base += 64) {
        int e = base + sub;
        if (e < cb) {
            int pkv = pp[e];                       // 16 lanes same addr -> 1 txn
            int r = pkv & 131071;
            int cl = (pkv >> 17) & 255;
            float v = h1p[(size_t)r * F_HID + lane];  // 64B line per edge
            atomicAdd(&acc[cl * F_HID + lane], v);     // ds_add_f32
        }
    }
    __syncthreads();

    // epilogue: 64 nodes per pass (sub = node slot), 4 passes
    for (int gl = sub; gl < 256; gl += 64) {
        int g = b * 256 + gl;
        if (g >= n) continue;
        float dc = rsqrtf((float)cnt[g] + 1.0f);
        float v = (acc[gl * F_HID + lane] + h1p[(size_t)g * F_HID + lane]) * dc + b1[lane];
        v = fmaxf(v, 0.0f);
        float tt = v * W2[lane];
        tt += __shfl_xor(tt, 1, 16);
        tt += __shfl_xor(tt, 2, 16);
        tt += __shfl_xor(tt, 4, 16);
        tt += __shfl_xor(tt, 8, 16);
        if (lane == 0) sp[g] = tt * dc;   // pre-scale by src norm for layer 2
    }
}

// layer-2 aggregation: scalar LDS atomics, fused sigmoid
__global__ __launch_bounds__(PB) void agg2_kernel(
    const int* __restrict__ cursor, const int* __restrict__ packed,
    const float* __restrict__ sp, const int* __restrict__ cnt,
    const float* __restrict__ b2, float* __restrict__ out,
    int capB, int n) {
    __shared__ float a2[256];
    int b = blockIdx.x, t = threadIdx.x;
    if (t < 256) a2[t] = 0.0f;
    __syncthreads();
    int cb = min(cursor[b], capB);
    const int* pp = packed + (size_t)b * capB;
    for (int e = t; e < cb; e += PB) {
        int pkv = pp[e];
        atomicAdd(&a2[(pkv >> 17) & 255], sp[pkv & 131071]);
    }
    __syncthreads();
    if (t < 256) {
        int g = b * 256 + t;
        if (g < n) {
            float v = (a2[t] + sp[g]) * rsqrtf((float)cnt[g] + 1.0f) + b2[0];
            out[g] = 1.0f / (1.0f + __expf(-v));
        }
    }
}

// ===========================================================================
// Shared: h1p = (x @ W1) * dinv[node]
// ===========================================================================
__global__ __launch_bounds__(256) void gemm1_kernel(const float* __restrict__ x,
                                                    const float* __restrict__ W1,
                                                    const int* __restrict__ cnt,
                                                    float* __restrict__ h1p, int n) {
    __shared__ float sW[F_IN * F_HID];
    int tid = threadIdx.x;
    for (int i = tid; i < F_IN * F_HID; i += 256) sW[i] = W1[i];
    __syncthreads();

    int node = blockIdx.x * 256 + tid;
    if (node >= n) return;

    const float4* xr = (const float4*)(x + (size_t)node * F_IN);
    float acc[F_HID];
#pragma unroll
    for (int j = 0; j < F_HID; j++) acc[j] = 0.0f;

#pragma unroll 4
    for (int k4 = 0; k4 < F_IN / 4; k4++) {
        float4 xv = xr[k4];
        const float* w0 = &sW[(k4 * 4 + 0) * F_HID];
        const float* w1 = &sW[(k4 * 4 + 1) * F_HID];
        const float* w2 = &sW[(k4 * 4 + 2) * F_HID];
        const float* w3 = &sW[(k4 * 4 + 3) * F_HID];
#pragma unroll
        for (int j = 0; j < F_HID; j++) {
            acc[j] += xv.x * w0[j] + xv.y * w1[j] + xv.z * w2[j] + xv.w * w3[j];
        }
    }

    float d = rsqrtf((float)cnt[node] + 1.0f);
    float4* outp = (float4*)(h1p + (size_t)node * F_HID);
    outp[0] = make_float4(acc[0] * d, acc[1] * d, acc[2] * d, acc[3] * d);
    outp[1] = make_float4(acc[4] * d, acc[5] * d, acc[6] * d, acc[7] * d);
    outp[2] = make_float4(acc[8] * d, acc[9] * d, acc[10] * d, acc[11] * d);
    outp[3] = make_float4(acc[12] * d, acc[13] * d, acc[14] * d, acc[15] * d);
}

// ===========================================================================
// FALLBACK (proven R4): fixed-capacity per-node buckets + 16-lane gathers
// ===========================================================================
__global__ void bucket_scatter_kernel(const int* __restrict__ row,
                                      const int* __restrict__ col,
                                      int* __restrict__ cnt,
                                      int* __restrict__ eidx,
                                      int cap, int n_edges) {
    int e = blockIdx.x * blockDim.x + threadIdx.x;
    if (e < n_edges) {
        int c = col[e];
        int p = atomicAdd(&cnt[c], 1);
        if (p < cap) eidx[(size_t)c * cap + p] = row[e];
    }
}

__global__ __launch_bounds__(256) void gather1_kernel(const int* __restrict__ cnt,
                                                      const int* __restrict__ eidx,
                                                      const float* __restrict__ h1p,
                                                      const float* __restrict__ b1,
                                                      const float* __restrict__ W2,
                                                      float* __restrict__ sp,
                                                      int cap, int n) {
    int g = (blockIdx.x * 256 + threadIdx.x) >> 4;
    int lane = threadIdx.x & 15;
    if (g >= n) return;
    int start = g * cap;
    int end = start + min(cnt[g], cap);

    float acc = 0.0f;
    for (int base = start; base < end; base += 16) {
        int e = base + lane;
        int r = (e < end) ? eidx[e] : 0;
        int m_cnt = min(16, end - base);
        for (int m = 0; m < m_cnt; m++) {
            int rm = __shfl(r, m, 16);
            acc += h1p[(size_t)rm * F_HID + lane];
        }
    }

    float dc = rsqrtf((float)cnt[g] + 1.0f);
    float v = (acc + h1p[(size_t)g * F_HID + lane]) * dc + b1[lane];
    v = fmaxf(v, 0.0f);
    float t = v * W2[lane];
    t += __shfl_xor(t, 1, 16);
    t += __shfl_xor(t, 2, 16);
    t += __shfl_xor(t, 4, 16);
    t += __shfl_xor(t, 8, 16);
    if (lane == 0) sp[g] = t * dc;
}

__global__ __launch_bounds__(256) void gather2_kernel(const int* __restrict__ cnt,
                                                      const int* __restrict__ eidx,
                                                      const float* __restrict__ sp,
                                                      const float* __restrict__ b2,
                                                      float* __restrict__ out,
                                                      int cap, int n) {
    int g = (blockIdx.x * 256 + threadIdx.x) >> 4;
    int lane = threadIdx.x & 15;
    if (g >= n) return;
    int start = g * cap;
    int end = start + min(cnt[g], cap);

    float acc = 0.0f;
    for (int e = start + lane; e < end; e += 16) {
        acc += sp[eidx[e]];
    }
    acc += __shfl_xor(acc, 1, 16);
    acc += __shfl_xor(acc, 2, 16);
    acc += __shfl_xor(acc, 4, 16);
    acc += __shfl_xor(acc, 8, 16);
    if (lane == 0) {
        float v = (acc + sp[g]) * rsqrtf((float)cnt[g] + 1.0f) + b2[0];
        out[g] = 1.0f / (1.0f + __expf(-v));
    }
}

extern "C" void kernel_launch(void* const* d_in, const int* in_sizes, int n_in,
                              void* d_out, int out_size, void* d_ws, size_t ws_size,
                              hipStream_t stream) {
    const float* x  = (const float*)d_in[0];
    const int*   ei = (const int*)d_in[1];  // [2, E] flat: row then col
    const float* W1 = (const float*)d_in[2];
    const float* b1 = (const float*)d_in[3];
    const float* W2 = (const float*)d_in[4];
    const float* b2 = (const float*)d_in[5];
    float* out = (float*)d_out;

    const int n = in_sizes[0] / F_IN;      // 100000
    const int n_edges = in_sizes[1] / 2;   // 3200000
    const int* row = ei;
    const int* col = ei + n_edges;

    // Workspace (4B words): cnt[S] | sp[S] | h1p[16S] | tail
    const size_t S = ((size_t)n + 511) & ~(size_t)511;
    const size_t words = ws_size / 4;
    int*   cnt = (int*)d_ws;
    float* sp  = (float*)(cnt + S);
    float* h1p = sp + S;
    int*   tail = (int*)(h1p + 16 * S);
    const size_t tail_words = (words > 18 * S) ? (words - 18 * S) : 0;

    const int B = 256;
    const int gridE = (n_edges + B - 1) / B;
    const int gridN = (n + B - 1) / B;

    const int NB = (n + 255) >> 8;                     // buckets of 256 nodes
    int meanB = (NB > 0) ? (n_edges / NB) : 0;
    int capB = ((meanB + meanB / 8 + 1024) + 15) & ~15;  // +~12% + slack
    size_t need_new = (size_t)NBMAX + (size_t)NB * (size_t)capB;

    if (n <= 131072 && NB <= NBMAX && tail_words >= need_new) {
        // -------- PATH NEW: partition + LDS-atomic aggregation --------
        int* cursor = tail;                // [NBMAX]
        int* packed = cursor + NBMAX;      // [NB * capB]

        hipMemsetAsync(cursor, 0, NBMAX * sizeof(int), stream);
        int ntiles = (n_edges + PT - 1) / PT;
        int pgrid = min(256, ntiles);
        partition_kernel<<<pgrid, PB, 0, stream>>>(row, col, cursor, packed,
                                                   capB, NB, n_edges);
        bucket_count_kernel<<<NB, PB, 0, stream>>>(cursor, packed, cnt, capB, n);
        gemm1_kernel<<<gridN, B, 0, stream>>>(x, W1, cnt, h1p, n);
        agg1_kernel<<<NB, PB, 0, stream>>>(cursor, packed, h1p, cnt, b1, W2, sp,
                                           capB, n);
        agg2_kernel<<<NB, PB, 0, stream>>>(cursor, packed, sp, cnt, b2, out,
                                           capB, n);
    } else {
        // -------- FALLBACK (R4): per-node fixed-cap buckets --------
        int cap = (int)min((size_t)96, tail_words / (size_t)(n > 0 ? n : 1));
        int* eidx = tail;
        const int gridG = (n * 16 + B - 1) / B;
        hipMemsetAsync(cnt, 0, (size_t)n * sizeof(int), stream);
        bucket_scatter_kernel<<<gridE, B, 0, stream>>>(row, col, cnt, eidx, cap, n_edges);
        gemm1_kernel<<<gridN, B, 0, stream>>>(x, W1, cnt, h1p, n);
        gather1_kernel<<<gridG, B, 0, stream>>>(cnt, eidx, h1p, b1, W2, sp, cap, n);
        gather2_kernel<<<gridG, B, 0, stream>>>(cnt, eidx, sp, b2, out, cap, n);
    }
}

// Round 6
// 212.449 us; speedup vs baseline: 2.4205x; 2.4205x over previous
//
#include <hip/hip_runtime.h>
#include <hip/hip_fp16.h>
#include <cstdint>

#define F_IN 128
#define F_HID 16
#define PB 1024           // partition block threads
#define PT 4096           // edges per partition tile
#define NBMAX 512         // max buckets (nodes/256), n <= 131072
#define CAPMAX 12288      // max bucket capacity (LDS sort buffer, 48 KB)

// ===========================================================================
// Phase 1: counting-sort partition into 256-node dst buckets.
// Packed edge word: r | (c&255)<<17  (needs n <= 2^17).
// ===========================================================================
__global__ __launch_bounds__(PB) void partition_kernel(
    const int* __restrict__ row, const int* __restrict__ col,
    int* __restrict__ cursor,        // [NBMAX], zeroed
    int* __restrict__ packed_out,    // [NB * capB]
    int capB, int NB, int n_edges) {
    __shared__ int sh_hist[NBMAX];
    __shared__ int sh_scan[NBMAX];
    __shared__ int sh_cur[NBMAX];
    __shared__ int sh_base[NBMAX];
    __shared__ int sh_packed[PT];
    __shared__ unsigned short sh_bkt[PT];

    int t = threadIdx.x;
    int ntiles = (n_edges + PT - 1) / PT;

    for (int tile = blockIdx.x; tile < ntiles; tile += gridDim.x) {
        int tbase = tile * PT;
        int tcnt = min(PT, n_edges - tbase);

        if (t < NBMAX) sh_hist[t] = 0;
        __syncthreads();

        int pk[4], bb[4];
#pragma unroll
        for (int k = 0; k < 4; k++) {
            int e = tbase + t + k * PB;
            bb[k] = -1;
            if (e < n_edges) {
                int r = row[e];
                int c = col[e];
                bb[k] = c >> 8;
                pk[k] = r | ((c & 255) << 17);
                atomicAdd(&sh_hist[bb[k]], 1);
            }
        }
        __syncthreads();

        if (t < NBMAX) sh_scan[t] = sh_hist[t];
        __syncthreads();
        for (int off = 1; off < NBMAX; off <<= 1) {
            int v = 0;
            if (t < NBMAX && t >= off) v = sh_scan[t - off];
            __syncthreads();
            if (t < NBMAX) sh_scan[t] += v;
            __syncthreads();
        }
        if (t < NBMAX) {
            int h = sh_hist[t];
            sh_cur[t] = sh_scan[t] - h;
            sh_base[t] = (h > 0 && t < NB) ? atomicAdd(&cursor[t], h) : 0;
        }
        __syncthreads();

#pragma unroll
        for (int k = 0; k < 4; k++) {
            if (bb[k] >= 0) {
                int p = atomicAdd(&sh_cur[bb[k]], 1);
                sh_packed[p] = pk[k];
                sh_bkt[p] = (unsigned short)bb[k];
            }
        }
        __syncthreads();

#pragma unroll
        for (int k = 0; k < 4; k++) {
            int p = t + k * PB;
            if (p < tcnt) {
                int b = sh_bkt[p];
                int off = p - (sh_scan[b] - sh_hist[b]);
                int gp = sh_base[b] + off;
                if (gp < capB) packed_out[(size_t)b * capB + gp] = sh_packed[p];
            }
        }
        __syncthreads();
    }
}

// ===========================================================================
// Phase 2: per-bucket counting sort to node-contiguous order (in place).
// Emits cnt[g] and rowptr[g] (global word index of node g's run).
// ===========================================================================
__global__ __launch_bounds__(PB) void bucket_sort_kernel(
    const int* __restrict__ cursor, int* __restrict__ packed,
    int* __restrict__ cnt, int* __restrict__ rowptr, int capB, int n) {
    __shared__ int sdata[CAPMAX];
    __shared__ int hist[256];
    __shared__ int incl[256];
    __shared__ int cur[256];

    int b = blockIdx.x, t = threadIdx.x;
    int cb = min(cursor[b], capB);
    int* pp = packed + (size_t)b * capB;

    if (t < 256) hist[t] = 0;
    __syncthreads();
    for (int i = t; i < cb; i += PB) {
        int v = pp[i];
        sdata[i] = v;
        atomicAdd(&hist[(v >> 17) & 255], 1);
    }
    __syncthreads();

    if (t < 256) incl[t] = hist[t];
    __syncthreads();
    for (int off = 1; off < 256; off <<= 1) {
        int u = 0;
        if (t < 256 && t >= off) u = incl[t - off];
        __syncthreads();
        if (t < 256) incl[t] += u;
        __syncthreads();
    }
    if (t < 256) {
        int excl = incl[t] - hist[t];
        cur[t] = excl;
        int g = b * 256 + t;
        if (g < n) {
            cnt[g] = hist[t];
            rowptr[g] = b * capB + excl;
        }
    }
    __syncthreads();

    // scatter back to global, node-contiguous, stripped to r only
    for (int i = t; i < cb; i += PB) {
        int v = sdata[i];
        int p = atomicAdd(&cur[(v >> 17) & 255], 1);
        pp[p] = v & 131071;
    }
}

// ===========================================================================
// Phase 3: h1p = fp16( (x @ W1) * dinv[node] )
// ===========================================================================
__global__ __launch_bounds__(256) void gemm1_kernel(const float* __restrict__ x,
                                                    const float* __restrict__ W1,
                                                    const int* __restrict__ cnt,
                                                    __half* __restrict__ h1p, int n) {
    __shared__ float sW[F_IN * F_HID];
    int tid = threadIdx.x;
    for (int i = tid; i < F_IN * F_HID; i += 256) sW[i] = W1[i];
    __syncthreads();

    int node = blockIdx.x * 256 + tid;
    if (node >= n) return;

    const float4* xr = (const float4*)(x + (size_t)node * F_IN);
    float acc[F_HID];
#pragma unroll
    for (int j = 0; j < F_HID; j++) acc[j] = 0.0f;

#pragma unroll 4
    for (int k4 = 0; k4 < F_IN / 4; k4++) {
        float4 xv = xr[k4];
        const float* w0 = &sW[(k4 * 4 + 0) * F_HID];
        const float* w1 = &sW[(k4 * 4 + 1) * F_HID];
        const float* w2 = &sW[(k4 * 4 + 2) * F_HID];
        const float* w3 = &sW[(k4 * 4 + 3) * F_HID];
#pragma unroll
        for (int j = 0; j < F_HID; j++) {
            acc[j] += xv.x * w0[j] + xv.y * w1[j] + xv.z * w2[j] + xv.w * w3[j];
        }
    }

    float d = rsqrtf((float)cnt[node] + 1.0f);
    __half2 hv[8];
#pragma unroll
    for (int j = 0; j < 8; j++) {
        hv[j] = __floats2half2_rn(acc[2 * j] * d, acc[2 * j + 1] * d);
    }
    float4* o4 = (float4*)(h1p + (size_t)node * F_HID);  // 32B/node, aligned
    o4[0] = *(float4*)&hv[0];
    o4[1] = *(float4*)&hv[4];
}

// ===========================================================================
// Phase 4: layer-1 gather (16 lanes per dst node) + bias + ReLU + @W2 fused
// ===========================================================================
__global__ __launch_bounds__(256) void gather1_kernel(const int* __restrict__ rowptr,
                                                      const int* __restrict__ cnt,
                                                      const int* __restrict__ eidx,
                                                      const __half* __restrict__ h1p,
                                                      const float* __restrict__ b1,
                                                      const float* __restrict__ W2,
                                                      float* __restrict__ sp, int n) {
    int g = (blockIdx.x * 256 + threadIdx.x) >> 4;
    int lane = threadIdx.x & 15;
    if (g >= n) return;
    int start = rowptr[g];
    int end = start + cnt[g];

    float acc = 0.0f;
    for (int base = start; base < end; base += 16) {
        int rem = end - base;
        int e = base + ((lane < rem) ? lane : 0);
        int r = eidx[e];
        if (rem >= 16) {
#pragma unroll
            for (int m = 0; m < 16; m++) {
                int rm = __shfl(r, m, 16);
                acc += (float)h1p[(size_t)rm * F_HID + lane];
            }
        } else {
            for (int m = 0; m < rem; m++) {
                int rm = __shfl(r, m, 16);
                acc += (float)h1p[(size_t)rm * F_HID + lane];
            }
        }
    }

    float dc = rsqrtf((float)cnt[g] + 1.0f);
    float v = (acc + (float)h1p[(size_t)g * F_HID + lane]) * dc + b1[lane];
    v = fmaxf(v, 0.0f);                 // ReLU
    float t = v * W2[lane];             // fused [16,1] GEMM
    t += __shfl_xor(t, 1, 16);
    t += __shfl_xor(t, 2, 16);
    t += __shfl_xor(t, 4, 16);
    t += __shfl_xor(t, 8, 16);
    if (lane == 0) sp[g] = t * dc;      // pre-scale by src norm for layer 2
}

// ===========================================================================
// Phase 5: layer-2 gather + sigmoid
// ===========================================================================
__global__ __launch_bounds__(256) void gather2_kernel(const int* __restrict__ rowptr,
                                                      const int* __restrict__ cnt,
                                                      const int* __restrict__ eidx,
                                                      const float* __restrict__ sp,
                                                      const float* __restrict__ b2,
                                                      float* __restrict__ out, int n) {
    int g = (blockIdx.x * 256 + threadIdx.x) >> 4;
    int lane = threadIdx.x & 15;
    if (g >= n) return;
    int start = rowptr[g];
    int end = start + cnt[g];

    float acc = 0.0f;
    for (int e = start + lane; e < end; e += 16) {
        acc += sp[eidx[e]];
    }
    acc += __shfl_xor(acc, 1, 16);
    acc += __shfl_xor(acc, 2, 16);
    acc += __shfl_xor(acc, 4, 16);
    acc += __shfl_xor(acc, 8, 16);
    if (lane == 0) {
        float v = (acc + sp[g]) * rsqrtf((float)cnt[g] + 1.0f) + b2[0];
        out[g] = 1.0f / (1.0f + __expf(-v));
    }
}

// ===========================================================================
// FALLBACK (proven R4): fixed-cap per-node buckets, fp32 h1p
// ===========================================================================
__global__ void bucket_scatter_kernel(const int* __restrict__ row,
                                      const int* __restrict__ col,
                                      int* __restrict__ cnt,
                                      int* __restrict__ eidx,
                                      int cap, int n_edges) {
    int e = blockIdx.x * blockDim.x + threadIdx.x;
    if (e < n_edges) {
        int c = col[e];
        int p = atomicAdd(&cnt[c], 1);
        if (p < cap) eidx[(size_t)c * cap + p] = row[e];
    }
}

__global__ __launch_bounds__(256) void gemm1f_kernel(const float* __restrict__ x,
                                                     const float* __restrict__ W1,
                                                     const int* __restrict__ cnt,
                                                     float* __restrict__ h1p, int n) {
    __shared__ float sW[F_IN * F_HID];
    int tid = threadIdx.x;
    for (int i = tid; i < F_IN * F_HID; i += 256) sW[i] = W1[i];
    __syncthreads();
    int node = blockIdx.x * 256 + tid;
    if (node >= n) return;
    const float4* xr = (const float4*)(x + (size_t)node * F_IN);
    float acc[F_HID];
#pragma unroll
    for (int j = 0; j < F_HID; j++) acc[j] = 0.0f;
#pragma unroll 4
    for (int k4 = 0; k4 < F_IN / 4; k4++) {
        float4 xv = xr[k4];
        const float* w0 = &sW[(k4 * 4 + 0) * F_HID];
        const float* w1 = &sW[(k4 * 4 + 1) * F_HID];
        const float* w2 = &sW[(k4 * 4 + 2) * F_HID];
        const float* w3 = &sW[(k4 * 4 + 3) * F_HID];
#pragma unroll
        for (int j = 0; j < F_HID; j++) {
            acc[j] += xv.x * w0[j] + xv.y * w1[j] + xv.z * w2[j] + xv.w * w3[j];
        }
    }
    float d = rsqrtf((float)cnt[node] + 1.0f);
    float4* outp = (float4*)(h1p + (size_t)node * F_HID);
    outp[0] = make_float4(acc[0] * d, acc[1] * d, acc[2] * d, acc[3] * d);
    outp[1] = make_float4(acc[4] * d, acc[5] * d, acc[6] * d, acc[7] * d);
    outp[2] = make_float4(acc[8] * d, acc[9] * d, acc[10] * d, acc[11] * d);
    outp[3] = make_float4(acc[12] * d, acc[13] * d, acc[14] * d, acc[15] * d);
}

__global__ __launch_bounds__(256) void fb_gather1_kernel(const int* __restrict__ cnt,
                                                         const int* __restrict__ eidx,
                                                         const float* __restrict__ h1p,
                                                         const float* __restrict__ b1,
                                                         const float* __restrict__ W2,
                                                         float* __restrict__ sp,
                                                         int cap, int n) {
    int g = (blockIdx.x * 256 + threadIdx.x) >> 4;
    int lane = threadIdx.x & 15;
    if (g >= n) return;
    int start = g * cap;
    int end = start + min(cnt[g], cap);
    float acc = 0.0f;
    for (int base = start; base < end; base += 16) {
        int e = base + lane;
        int r = (e < end) ? eidx[e] : 0;
        int m_cnt = min(16, end - base);
        for (int m = 0; m < m_cnt; m++) {
            int rm = __shfl(r, m, 16);
            acc += h1p[(size_t)rm * F_HID + lane];
        }
    }
    float dc = rsqrtf((float)cnt[g] + 1.0f);
    float v = (acc + h1p[(size_t)g * F_HID + lane]) * dc + b1[lane];
    v = fmaxf(v, 0.0f);
    float t = v * W2[lane];
    t += __shfl_xor(t, 1, 16);
    t += __shfl_xor(t, 2, 16);
    t += __shfl_xor(t, 4, 16);
    t += __shfl_xor(t, 8, 16);
    if (lane == 0) sp[g] = t * dc;
}

__global__ __launch_bounds__(256) void fb_gather2_kernel(const int* __restrict__ cnt,
                                                         const int* __restrict__ eidx,
                                                         const float* __restrict__ sp,
                                                         const float* __restrict__ b2,
                                                         float* __restrict__ out,
                                                         int cap, int n) {
    int g = (blockIdx.x * 256 + threadIdx.x) >> 4;
    int lane = threadIdx.x & 15;
    if (g >= n) return;
    int start = g * cap;
    int end = start + min(cnt[g], cap);
    float acc = 0.0f;
    for (int e = start + lane; e < end; e += 16) {
        acc += sp[eidx[e]];
    }
    acc += __shfl_xor(acc, 1, 16);
    acc += __shfl_xor(acc, 2, 16);
    acc += __shfl_xor(acc, 4, 16);
    acc += __shfl_xor(acc, 8, 16);
    if (lane == 0) {
        float v = (acc + sp[g]) * rsqrtf((float)cnt[g] + 1.0f) + b2[0];
        out[g] = 1.0f / (1.0f + __expf(-v));
    }
}

extern "C" void kernel_launch(void* const* d_in, const int* in_sizes, int n_in,
                              void* d_out, int out_size, void* d_ws, size_t ws_size,
                              hipStream_t stream) {
    const float* x  = (const float*)d_in[0];
    const int*   ei = (const int*)d_in[1];  // [2, E] flat: row then col
    const float* W1 = (const float*)d_in[2];
    const float* b1 = (const float*)d_in[3];
    const float* W2 = (const float*)d_in[4];
    const float* b2 = (const float*)d_in[5];
    float* out = (float*)d_out;

    const int n = in_sizes[0] / F_IN;      // 100000
    const int n_edges = in_sizes[1] / 2;   // 3200000
    const int* row = ei;
    const int* col = ei + n_edges;

    const size_t S = ((size_t)n + 511) & ~(size_t)511;
    const size_t words = ws_size / 4;

    const int B = 256;
    const int gridE = (n_edges + B - 1) / B;
    const int gridN = (n + B - 1) / B;
    const int gridG = (n * 16 + B - 1) / B;

    const int NB = (n + 255) >> 8;
    int meanB = (NB > 0) ? (n_edges / NB) : 0;
    int capB = ((meanB + meanB / 8 + 1024) + 15) & ~15;  // mean + 12% + slack
    // New-path layout (words): cnt[S] | rowptr[S] | sp[S] | h1p(half16)[8S] |
    //                          cursor[NBMAX] | packed[NB*capB]
    size_t need_new = 11 * S + (size_t)NBMAX + (size_t)NB * (size_t)capB;

    if (n <= 131072 && NB <= NBMAX && capB <= CAPMAX && words >= need_new) {
        int*    cnt    = (int*)d_ws;
        int*    rowptr = cnt + S;
        float*  sp     = (float*)(rowptr + S);
        __half* h1p    = (__half*)(sp + S);
        int*    cursor = (int*)((float*)(sp + S) + 8 * S);
        int*    packed = cursor + NBMAX;

        hipMemsetAsync(cursor, 0, NBMAX * sizeof(int), stream);
        int ntiles = (n_edges + PT - 1) / PT;
        int pgrid = min(256, ntiles);
        partition_kernel<<<pgrid, PB, 0, stream>>>(row, col, cursor, packed,
                                                   capB, NB, n_edges);
        bucket_sort_kernel<<<NB, PB, 0, stream>>>(cursor, packed, cnt, rowptr,
                                                  capB, n);
        gemm1_kernel<<<gridN, B, 0, stream>>>(x, W1, cnt, h1p, n);
        gather1_kernel<<<gridG, B, 0, stream>>>(rowptr, cnt, packed, h1p, b1, W2,
                                                sp, n);
        gather2_kernel<<<gridG, B, 0, stream>>>(rowptr, cnt, packed, sp, b2, out, n);
    } else {
        // FALLBACK (R4): cnt[S] | sp[S] | h1pf[16S] | eidx[n*cap]
        int*   cnt  = (int*)d_ws;
        float* sp   = (float*)(cnt + S);
        float* h1pf = sp + S;
        int*   eidx = (int*)(h1pf + 16 * S);
        size_t tail_words = (words > 18 * S) ? (words - 18 * S) : 0;
        int cap = (int)min((size_t)96, tail_words / (size_t)(n > 0 ? n : 1));

        hipMemsetAsync(cnt, 0, (size_t)n * sizeof(int), stream);
        bucket_scatter_kernel<<<gridE, B, 0, stream>>>(row, col, cnt, eidx, cap, n_edges);
        gemm1f_kernel<<<gridN, B, 0, stream>>>(x, W1, cnt, h1pf, n);
        fb_gather1_kernel<<<gridG, B, 0, stream>>>(cnt, eidx, h1pf, b1, W2, sp, cap, n);
        fb_gather2_kernel<<<gridG, B, 0, stream>>>(cnt, eidx, sp, b2, out, cap, n);
    }
}

// Round 7
// 199.719 us; speedup vs baseline: 2.5747x; 1.0637x over previous
//
#include <hip/hip_runtime.h>
#include <hip/hip_fp16.h>
#include <cstdint>

#define F_IN 128
#define F_HID 16
#define PB 1024           // partition block threads
#define PT 8192           // edges per partition tile
#define NBMAX 512         // max buckets (nodes/256), n <= 131072
#define CAPMAX 12288      // max bucket capacity (LDS sort buffer, 48 KB)

// ===========================================================================
// Phase 1: counting-sort partition into 256-node dst buckets.
// Packed edge word: r | (c&255)<<17  (needs n <= 2^17).
// Scan: wave-hierarchical shfl (2 barriers vs 18 for Hillis-Steele).
// ===========================================================================
__global__ __launch_bounds__(PB) void partition_kernel(
    const int* __restrict__ row, const int* __restrict__ col,
    int* __restrict__ cursor,        // [NBMAX], zeroed
    int* __restrict__ packed_out,    // [NB * capB]
    int capB, int NB, int n_edges) {
    __shared__ int sh_hist[NBMAX];
    __shared__ int sh_scan[NBMAX];
    __shared__ int sh_cur[NBMAX];
    __shared__ int sh_base[NBMAX];
    __shared__ int sh_wsum[16];
    __shared__ int sh_packed[PT];
    __shared__ unsigned short sh_bkt[PT];

    int t = threadIdx.x;
    int lane = t & 63;
    int wv = t >> 6;
    int ntiles = (n_edges + PT - 1) / PT;

    for (int tile = blockIdx.x; tile < ntiles; tile += gridDim.x) {
        int tbase = tile * PT;
        int tcnt = min(PT, n_edges - tbase);

        if (t < NBMAX) sh_hist[t] = 0;
        __syncthreads();

        int pk[8], bb[8];
#pragma unroll
        for (int k = 0; k < 8; k++) {
            int e = tbase + t + k * PB;
            bb[k] = -1;
            if (e < n_edges) {
                int r = row[e];
                int c = col[e];
                bb[k] = c >> 8;
                pk[k] = r | ((c & 255) << 17);
                atomicAdd(&sh_hist[bb[k]], 1);
            }
        }
        __syncthreads();

        // wave-hierarchical inclusive scan of sh_hist[0..511]
        {
            int v = (t < NBMAX) ? sh_hist[t] : 0;
            int incl = v;
#pragma unroll
            for (int off = 1; off < 64; off <<= 1) {
                int u = __shfl_up(incl, off, 64);
                if (lane >= off) incl += u;
            }
            if (lane == 63) sh_wsum[wv] = incl;
            __syncthreads();
            if (t < 16) {
                int s = sh_wsum[t];
#pragma unroll
                for (int off = 1; off < 16; off <<= 1) {
                    int u = __shfl_up(s, off, 16);
                    if (t >= off) s += u;
                }
                sh_wsum[t] = s;
            }
            __syncthreads();
            int wexcl = (wv > 0) ? sh_wsum[wv - 1] : 0;
            if (t < NBMAX) sh_scan[t] = incl + wexcl;
        }
        __syncthreads();

        if (t < NBMAX) {
            int h = sh_hist[t];
            sh_cur[t] = sh_scan[t] - h;
            sh_base[t] = (h > 0 && t < NB) ? atomicAdd(&cursor[t], h) : 0;
        }
        __syncthreads();

        // LDS reorder scatter
#pragma unroll
        for (int k = 0; k < 8; k++) {
            if (bb[k] >= 0) {
                int p = atomicAdd(&sh_cur[bb[k]], 1);
                sh_packed[p] = pk[k];
                sh_bkt[p] = (unsigned short)bb[k];
            }
        }
        __syncthreads();

        // write runs out bucket-contiguously
#pragma unroll
        for (int k = 0; k < 8; k++) {
            int p = t + k * PB;
            if (p < tcnt) {
                int b = sh_bkt[p];
                int off = p - (sh_scan[b] - sh_hist[b]);
                int gp = sh_base[b] + off;
                if (gp < capB) packed_out[(size_t)b * capB + gp] = sh_packed[p];
            }
        }
        __syncthreads();
    }
}

// ===========================================================================
// Phase 2: per-bucket counting sort to node-contiguous order (in place).
// Emits cnt[g] and rowptr[g]. Wave-hierarchical 256-wide scan.
// ===========================================================================
__global__ __launch_bounds__(PB) void bucket_sort_kernel(
    const int* __restrict__ cursor, int* __restrict__ packed,
    int* __restrict__ cnt, int* __restrict__ rowptr, int capB, int n) {
    __shared__ int sdata[CAPMAX];
    __shared__ int hist[256];
    __shared__ int scan_[256];
    __shared__ int cur[256];
    __shared__ int wsum[16];

    int b = blockIdx.x, t = threadIdx.x;
    int lane = t & 63;
    int wv = t >> 6;
    int cb = min(cursor[b], capB);
    int* pp = packed + (size_t)b * capB;

    if (t < 256) hist[t] = 0;
    __syncthreads();
    for (int i = t; i < cb; i += PB) {
        int v = pp[i];
        sdata[i] = v;
        atomicAdd(&hist[(v >> 17) & 255], 1);
    }
    __syncthreads();

    // wave-hierarchical inclusive scan of hist[0..255]
    {
        int v = (t < 256) ? hist[t] : 0;
        int incl = v;
#pragma unroll
        for (int off = 1; off < 64; off <<= 1) {
            int u = __shfl_up(incl, off, 64);
            if (lane >= off) incl += u;
        }
        if (lane == 63) wsum[wv] = incl;
        __syncthreads();
        if (t < 16) {
            int s = wsum[t];
#pragma unroll
            for (int off = 1; off < 16; off <<= 1) {
                int u = __shfl_up(s, off, 16);
                if (t >= off) s += u;
            }
            wsum[t] = s;
        }
        __syncthreads();
        int wexcl = (wv > 0) ? wsum[wv - 1] : 0;
        if (t < 256) scan_[t] = incl + wexcl;
    }
    __syncthreads();

    if (t < 256) {
        int excl = scan_[t] - hist[t];
        cur[t] = excl;
        int g = b * 256 + t;
        if (g < n) {
            cnt[g] = hist[t];
            rowptr[g] = b * capB + excl;
        }
    }
    __syncthreads();

    // scatter back to global, node-contiguous, stripped to r only
    for (int i = t; i < cb; i += PB) {
        int v = sdata[i];
        int p = atomicAdd(&cur[(v >> 17) & 255], 1);
        pp[p] = v & 131071;
    }
}

// ===========================================================================
// Phase 3: h1p = fp16( (x @ W1) * dinv[node] )
// ===========================================================================
__global__ __launch_bounds__(256) void gemm1_kernel(const float* __restrict__ x,
                                                    const float* __restrict__ W1,
                                                    const int* __restrict__ cnt,
                                                    __half* __restrict__ h1p, int n) {
    __shared__ float sW[F_IN * F_HID];
    int tid = threadIdx.x;
    for (int i = tid; i < F_IN * F_HID; i += 256) sW[i] = W1[i];
    __syncthreads();

    int node = blockIdx.x * 256 + tid;
    if (node >= n) return;

    const float4* xr = (const float4*)(x + (size_t)node * F_IN);
    float acc[F_HID];
#pragma unroll
    for (int j = 0; j < F_HID; j++) acc[j] = 0.0f;

#pragma unroll 4
    for (int k4 = 0; k4 < F_IN / 4; k4++) {
        float4 xv = xr[k4];
        const float* w0 = &sW[(k4 * 4 + 0) * F_HID];
        const float* w1 = &sW[(k4 * 4 + 1) * F_HID];
        const float* w2 = &sW[(k4 * 4 + 2) * F_HID];
        const float* w3 = &sW[(k4 * 4 + 3) * F_HID];
#pragma unroll
        for (int j = 0; j < F_HID; j++) {
            acc[j] += xv.x * w0[j] + xv.y * w1[j] + xv.z * w2[j] + xv.w * w3[j];
        }
    }

    float d = rsqrtf((float)cnt[node] + 1.0f);
    __half2 hv[8];
#pragma unroll
    for (int j = 0; j < 8; j++) {
        hv[j] = __floats2half2_rn(acc[2 * j] * d, acc[2 * j + 1] * d);
    }
    float4* o4 = (float4*)(h1p + (size_t)node * F_HID);
    o4[0] = *(float4*)&hv[0];
    o4[1] = *(float4*)&hv[4];
}

// ===========================================================================
// Phase 4: layer-1 gather, 8 lanes per dst node, half2 loads.
// ===========================================================================
__global__ __launch_bounds__(256) void gather1_kernel(const int* __restrict__ rowptr,
                                                      const int* __restrict__ cnt,
                                                      const int* __restrict__ eidx,
                                                      const __half* __restrict__ h1p,
                                                      const float* __restrict__ b1,
                                                      const float* __restrict__ W2,
                                                      float* __restrict__ sp, int n) {
    int g = (blockIdx.x * 256 + threadIdx.x) >> 3;  // dst node
    int l = threadIdx.x & 7;                        // feature-pair index
    if (g >= n) return;
    int start = rowptr[g];
    int end = start + cnt[g];

    float ax = 0.0f, ay = 0.0f;
    for (int base = start; base < end; base += 8) {
        int rem = end - base;
        int e = base + ((l < rem) ? l : 0);
        int r = eidx[e];
        if (rem >= 8) {
#pragma unroll
            for (int m = 0; m < 8; m++) {
                int rm = __shfl(r, m, 8);
                float2 f = __half22float2(*(const __half2*)(h1p + (size_t)rm * F_HID + 2 * l));
                ax += f.x; ay += f.y;
            }
        } else {
            for (int m = 0; m < rem; m++) {
                int rm = __shfl(r, m, 8);
                float2 f = __half22float2(*(const __half2*)(h1p + (size_t)rm * F_HID + 2 * l));
                ax += f.x; ay += f.y;
            }
        }
    }

    float dc = rsqrtf((float)cnt[g] + 1.0f);
    float2 fs = __half22float2(*(const __half2*)(h1p + (size_t)g * F_HID + 2 * l));
    float v0 = (ax + fs.x) * dc + b1[2 * l];
    float v1 = (ay + fs.y) * dc + b1[2 * l + 1];
    v0 = fmaxf(v0, 0.0f);
    v1 = fmaxf(v1, 0.0f);
    float t = v0 * W2[2 * l] + v1 * W2[2 * l + 1];  // fused [16,1] GEMM
    t += __shfl_xor(t, 1, 8);
    t += __shfl_xor(t, 2, 8);
    t += __shfl_xor(t, 4, 8);
    if (l == 0) sp[g] = t * dc;          // pre-scale by src norm for layer 2
}

// ===========================================================================
// Phase 5: layer-2 gather + sigmoid (16 lanes per node)
// ===========================================================================
__global__ __launch_bounds__(256) void gather2_kernel(const int* __restrict__ rowptr,
                                                      const int* __restrict__ cnt,
                                                      const int* __restrict__ eidx,
                                                      const float* __restrict__ sp,
                                                      const float* __restrict__ b2,
                                                      float* __restrict__ out, int n) {
    int g = (blockIdx.x * 256 + threadIdx.x) >> 4;
    int lane = threadIdx.x & 15;
    if (g >= n) return;
    int start = rowptr[g];
    int end = start + cnt[g];

    float acc = 0.0f;
    for (int e = start + lane; e < end; e += 16) {
        acc += sp[eidx[e]];
    }
    acc += __shfl_xor(acc, 1, 16);
    acc += __shfl_xor(acc, 2, 16);
    acc += __shfl_xor(acc, 4, 16);
    acc += __shfl_xor(acc, 8, 16);
    if (lane == 0) {
        float v = (acc + sp[g]) * rsqrtf((float)cnt[g] + 1.0f) + b2[0];
        out[g] = 1.0f / (1.0f + __expf(-v));
    }
}

// ===========================================================================
// FALLBACK (proven R4): fixed-cap per-node buckets, fp32 h1p
// ===========================================================================
__global__ void bucket_scatter_kernel(const int* __restrict__ row,
                                      const int* __restrict__ col,
                                      int* __restrict__ cnt,
                                      int* __restrict__ eidx,
                                      int cap, int n_edges) {
    int e = blockIdx.x * blockDim.x + threadIdx.x;
    if (e < n_edges) {
        int c = col[e];
        int p = atomicAdd(&cnt[c], 1);
        if (p < cap) eidx[(size_t)c * cap + p] = row[e];
    }
}

__global__ __launch_bounds__(256) void gemm1f_kernel(const float* __restrict__ x,
                                                     const float* __restrict__ W1,
                                                     const int* __restrict__ cnt,
                                                     float* __restrict__ h1p, int n) {
    __shared__ float sW[F_IN * F_HID];
    int tid = threadIdx.x;
    for (int i = tid; i < F_IN * F_HID; i += 256) sW[i] = W1[i];
    __syncthreads();
    int node = blockIdx.x * 256 + tid;
    if (node >= n) return;
    const float4* xr = (const float4*)(x + (size_t)node * F_IN);
    float acc[F_HID];
#pragma unroll
    for (int j = 0; j < F_HID; j++) acc[j] = 0.0f;
#pragma unroll 4
    for (int k4 = 0; k4 < F_IN / 4; k4++) {
        float4 xv = xr[k4];
        const float* w0 = &sW[(k4 * 4 + 0) * F_HID];
        const float* w1 = &sW[(k4 * 4 + 1) * F_HID];
        const float* w2 = &sW[(k4 * 4 + 2) * F_HID];
        const float* w3 = &sW[(k4 * 4 + 3) * F_HID];
#pragma unroll
        for (int j = 0; j < F_HID; j++) {
            acc[j] += xv.x * w0[j] + xv.y * w1[j] + xv.z * w2[j] + xv.w * w3[j];
        }
    }
    float d = rsqrtf((float)cnt[node] + 1.0f);
    float4* outp = (float4*)(h1p + (size_t)node * F_HID);
    outp[0] = make_float4(acc[0] * d, acc[1] * d, acc[2] * d, acc[3] * d);
    outp[1] = make_float4(acc[4] * d, acc[5] * d, acc[6] * d, acc[7] * d);
    outp[2] = make_float4(acc[8] * d, acc[9] * d, acc[10] * d, acc[11] * d);
    outp[3] = make_float4(acc[12] * d, acc[13] * d, acc[14] * d, acc[15] * d);
}

__global__ __launch_bounds__(256) void fb_gather1_kernel(const int* __restrict__ cnt,
                                                         const int* __restrict__ eidx,
                                                         const float* __restrict__ h1p,
                                                         const float* __restrict__ b1,
                                                         const float* __restrict__ W2,
                                                         float* __restrict__ sp,
                                                         int cap, int n) {
    int g = (blockIdx.x * 256 + threadIdx.x) >> 4;
    int lane = threadIdx.x & 15;
    if (g >= n) return;
    int start = g * cap;
    int end = start + min(cnt[g], cap);
    float acc = 0.0f;
    for (int base = start; base < end; base += 16) {
        int e = base + lane;
        int r = (e < end) ? eidx[e] : 0;
        int m_cnt = min(16, end - base);
        for (int m = 0; m < m_cnt; m++) {
            int rm = __shfl(r, m, 16);
            acc += h1p[(size_t)rm * F_HID + lane];
        }
    }
    float dc = rsqrtf((float)cnt[g] + 1.0f);
    float v = (acc + h1p[(size_t)g * F_HID + lane]) * dc + b1[lane];
    v = fmaxf(v, 0.0f);
    float t = v * W2[lane];
    t += __shfl_xor(t, 1, 16);
    t += __shfl_xor(t, 2, 16);
    t += __shfl_xor(t, 4, 16);
    t += __shfl_xor(t, 8, 16);
    if (lane == 0) sp[g] = t * dc;
}

__global__ __launch_bounds__(256) void fb_gather2_kernel(const int* __restrict__ cnt,
                                                         const int* __restrict__ eidx,
                                                         const float* __restrict__ sp,
                                                         const float* __restrict__ b2,
                                                         float* __restrict__ out,
                                                         int cap, int n) {
    int g = (blockIdx.x * 256 + threadIdx.x) >> 4;
    int lane = threadIdx.x & 15;
    if (g >= n) return;
    int start = g * cap;
    int end = start + min(cnt[g], cap);
    float acc = 0.0f;
    for (int e = start + lane; e < end; e += 16) {
        acc += sp[eidx[e]];
    }
    acc += __shfl_xor(acc, 1, 16);
    acc += __shfl_xor(acc, 2, 16);
    acc += __shfl_xor(acc, 4, 16);
    acc += __shfl_xor(acc, 8, 16);
    if (lane == 0) {
        float v = (acc + sp[g]) * rsqrtf((float)cnt[g] + 1.0f) + b2[0];
        out[g] = 1.0f / (1.0f + __expf(-v));
    }
}

extern "C" void kernel_launch(void* const* d_in, const int* in_sizes, int n_in,
                              void* d_out, int out_size, void* d_ws, size_t ws_size,
                              hipStream_t stream) {
    const float* x  = (const float*)d_in[0];
    const int*   ei = (const int*)d_in[1];  // [2, E] flat: row then col
    const float* W1 = (const float*)d_in[2];
    const float* b1 = (const float*)d_in[3];
    const float* W2 = (const float*)d_in[4];
    const float* b2 = (const float*)d_in[5];
    float* out = (float*)d_out;

    const int n = in_sizes[0] / F_IN;      // 100000
    const int n_edges = in_sizes[1] / 2;   // 3200000
    const int* row = ei;
    const int* col = ei + n_edges;

    const size_t S = ((size_t)n + 511) & ~(size_t)511;
    const size_t words = ws_size / 4;

    const int B = 256;
    const int gridE = (n_edges + B - 1) / B;
    const int gridN = (n + B - 1) / B;

    const int NB = (n + 255) >> 8;
    int meanB = (NB > 0) ? (n_edges / NB) : 0;
    int capB = ((meanB + meanB / 8 + 1024) + 15) & ~15;  // mean + 12% + slack
    // New-path layout (words): cnt[S] | rowptr[S] | sp[S] | h1p(half16)[8S] |
    //                          cursor[NBMAX] | packed[NB*capB]
    size_t need_new = 11 * S + (size_t)NBMAX + (size_t)NB * (size_t)capB;

    if (n <= 131072 && NB <= NBMAX && capB <= CAPMAX && words >= need_new) {
        int*    cnt    = (int*)d_ws;
        int*    rowptr = cnt + S;
        float*  sp     = (float*)(rowptr + S);
        __half* h1p    = (__half*)(sp + S);
        int*    cursor = (int*)((float*)(sp + S) + 8 * S);
        int*    packed = cursor + NBMAX;

        hipMemsetAsync(cursor, 0, NBMAX * sizeof(int), stream);
        int ntiles = (n_edges + PT - 1) / PT;
        int pgrid = min(2048, ntiles);
        partition_kernel<<<pgrid, PB, 0, stream>>>(row, col, cursor, packed,
                                                   capB, NB, n_edges);
        bucket_sort_kernel<<<NB, PB, 0, stream>>>(cursor, packed, cnt, rowptr,
                                                  capB, n);
        gemm1_kernel<<<gridN, B, 0, stream>>>(x, W1, cnt, h1p, n);
        int gridG1 = (n * 8 + B - 1) / B;   // 8 lanes per node
        gather1_kernel<<<gridG1, B, 0, stream>>>(rowptr, cnt, packed, h1p, b1, W2,
                                                 sp, n);
        int gridG2 = (n * 16 + B - 1) / B;  // 16 lanes per node
        gather2_kernel<<<gridG2, B, 0, stream>>>(rowptr, cnt, packed, sp, b2, out, n);
    } else {
        // FALLBACK (R4): cnt[S] | sp[S] | h1pf[16S] | eidx[n*cap]
        int*   cnt  = (int*)d_ws;
        float* sp   = (float*)(cnt + S);
        float* h1pf = sp + S;
        int*   eidx = (int*)(h1pf + 16 * S);
        size_t tail_words = (words > 18 * S) ? (words - 18 * S) : 0;
        int cap = (int)min((size_t)96, tail_words / (size_t)(n > 0 ? n : 1));
        const int gridG = (n * 16 + B - 1) / B;

        hipMemsetAsync(cnt, 0, (size_t)n * sizeof(int), stream);
        bucket_scatter_kernel<<<gridE, B, 0, stream>>>(row, col, cnt, eidx, cap, n_edges);
        gemm1f_kernel<<<gridN, B, 0, stream>>>(x, W1, cnt, h1pf, n);
        fb_gather1_kernel<<<gridG, B, 0, stream>>>(cnt, eidx, h1pf, b1, W2, sp, cap, n);
        fb_gather2_kernel<<<gridG, B, 0, stream>>>(cnt, eidx, sp, b2, out, cap, n);
    }
}